// Round 10
// baseline (268.404 us; speedup 1.0000x reference)
//
#include <hip/hip_runtime.h>

#define NNODES 40960
#define NEDGES 81920
#define NG     1024
#define NCOMBO 512
#define NHB    320      // NEDGES/256 histogram blocks
#define NGRP   4        // edge-groups per combo in k_msgg

// ---------- fused node encoder: x[n,:], then out_init[n,:] = bias + x@root ---
__global__ __launch_bounds__(256) void k_node(
    const int* __restrict__ nf, const float* __restrict__ emb,
    const float* __restrict__ root, const float* __restrict__ bias,
    float* __restrict__ x, float* __restrict__ out) {
    __shared__ float sx[4][64];
    const int t = threadIdx.x;
    const int ln = t >> 6;                 // local node 0..3
    const int d  = t & 63;
    const int n  = blockIdx.x * 4 + ln;
    const int* nfr = nf + n * 9;
    float acc = 0.f;
#pragma unroll
    for (int c = 0; c < 9; ++c) {
        int idx = nfr[c];
        acc += emb[((c << 7) + idx) * 64 + d];
    }
    x[n * 64 + d] = acc;
    sx[ln][d] = acc;
    __syncthreads();
    if (d < 32) {
        float o = bias[d];
#pragma unroll
        for (int k = 0; k < 64; ++k) o += sx[ln][k] * root[k * 32 + d];
        out[n * 32 + d] = o;
    }
}

// ---------- h1[c,:] = relu(etab[c] @ gW1), etab computed in-LDS ----------
__global__ __launch_bounds__(256) void k_h1(
    const float* __restrict__ bemb, const float* __restrict__ gW1,
    float* __restrict__ h1) {
    __shared__ float se[16];
    const int b = blockIdx.x, t = threadIdx.x;
    const int c = b >> 2;
    const int n = ((b & 3) << 8) + t;
    if (t < 16) {
        int f0 = c >> 6, f1 = (c >> 3) & 7, f2 = c & 7;
        se[t] = bemb[f0 * 16 + t] + bemb[(8 + f1) * 16 + t] +
                bemb[(16 + f2) * 16 + t];
    }
    __syncthreads();
    float acc = 0.f;
#pragma unroll
    for (int k = 0; k < 16; ++k) acc += se[k] * gW1[k * 1024 + n];
    h1[c * 1024 + n] = fmaxf(acc, 0.f);
}

// ---------- sort prep 1: cid + per-block LDS histogram (no hot global atomics)
__global__ void k_hist(const int* __restrict__ ef, int* __restrict__ cid,
                       int* __restrict__ bh) {
    __shared__ int lh[512];
    const int t = threadIdx.x, b = blockIdx.x;
    lh[t] = 0; lh[t + 256] = 0;
    __syncthreads();
    int e = b * 256 + t;
    int c = (ef[e * 3] << 6) | (ef[e * 3 + 1] << 3) | ef[e * 3 + 2];
    cid[e] = c;
    atomicAdd(&lh[c], 1);                      // LDS atomic
    __syncthreads();
    bh[b * 512 + t]       = lh[t];
    bh[b * 512 + 256 + t] = lh[t + 256];
}

// ---------- sort prep 2: exact offsets (1 block, 512 threads) ----------
// bh[b][c] becomes the global write base for block b's combo-c edges.
__global__ __launch_bounds__(512) void k_scan(int* __restrict__ bh,
                                              int* __restrict__ offs) {
    __shared__ int tmp[512];
    const int c = threadIdx.x;
    int s = 0;
    for (int b = 0; b < NHB; ++b) {            // prefix over blocks, per combo
        int v = bh[b * 512 + c];
        bh[b * 512 + c] = s;
        s += v;
    }
    tmp[c] = s;                                // total count of combo c
    __syncthreads();
    for (int d = 1; d < 512; d <<= 1) {        // inclusive scan over combos
        int add = (c >= d) ? tmp[c - d] : 0;
        __syncthreads();
        tmp[c] += add;
        __syncthreads();
    }
    int excl = tmp[c] - s;
    offs[c] = excl;
    if (c == 511) offs[512] = tmp[511];
    for (int b = 0; b < NHB; ++b) bh[b * 512 + c] += excl;
}

// ---------- sort prep 3: scatter into packed (src,dst) sorted by cid ---------
__global__ void k_scatter(const int* __restrict__ cid, const int* __restrict__ src,
                          const int* __restrict__ dst, const int* __restrict__ bh,
                          int2* __restrict__ esd) {
    __shared__ int cur[512];
    const int t = threadIdx.x, b = blockIdx.x;
    cur[t]       = bh[b * 512 + t];
    cur[t + 256] = bh[b * 512 + 256 + t];
    __syncthreads();
    int e = b * 256 + t;
    int p = atomicAdd(&cur[cid[e]], 1);        // LDS atomic, per-block
    esd[p] = make_int2(src[e], dst[e]);
}

// ---------- tiled GEMM, 64x64 block tile, 4x4 micro tile, split-K over z ------
template <int BM, int BN, int BK, int TM, int TN>
__global__ __launch_bounds__(256)
void k_gemm_tiled(const float* __restrict__ A, const float* __restrict__ B,
                  const float* __restrict__ bias, float* __restrict__ C,
                  float* __restrict__ Cp, int M, int N, int K, int KS, int relu) {
    constexpr int TX = BN / TN;                 // 16
    constexpr int TY = BM / TM;                 // 16
    static_assert(TX * TY == 256, "block must be 256 threads");
    __shared__ float As[BK][BM + 4];            // transposed A tile
    __shared__ float Bs[BK][BN + 4];
    const int tx = threadIdx.x % TX, ty = threadIdx.x / TX;
    const int row0 = blockIdx.y * BM, col0 = blockIdx.x * BN;
    const int z = blockIdx.z;
    const int k_begin = z * KS, k_end = k_begin + KS;

    const int am = threadIdx.x >> 2;            // 0..63
    const int ak = (threadIdx.x & 3) << 2;      // 0,4,8,12
    const int bk = threadIdx.x >> 4;            // 0..15
    const int bn = (threadIdx.x & 15) << 2;     // 0..60

    float acc[TM][TN] = {};
    for (int k0 = k_begin; k0 < k_end; k0 += BK) {
        float4 av = *reinterpret_cast<const float4*>(&A[(row0 + am) * K + k0 + ak]);
        float4 bv = *reinterpret_cast<const float4*>(&B[(k0 + bk) * N + col0 + bn]);
        As[ak + 0][am] = av.x;
        As[ak + 1][am] = av.y;
        As[ak + 2][am] = av.z;
        As[ak + 3][am] = av.w;
        *reinterpret_cast<float4*>(&Bs[bk][bn]) = bv;
        __syncthreads();
#pragma unroll
        for (int k = 0; k < BK; ++k) {
            float a[TM], b[TN];
            *reinterpret_cast<float4*>(a) =
                *reinterpret_cast<const float4*>(&As[k][ty * TM]);
            *reinterpret_cast<float4*>(b) =
                *reinterpret_cast<const float4*>(&Bs[k][tx * TN]);
#pragma unroll
            for (int i = 0; i < TM; ++i)
#pragma unroll
                for (int j = 0; j < TN; ++j) acc[i][j] += a[i] * b[j];
        }
        __syncthreads();
    }

    const int MN = M * N;
    if (gridDim.z == 1) {
#pragma unroll
        for (int i = 0; i < TM; ++i) {
            int r = row0 + ty * TM + i;
            float4 v;
            v.x = acc[i][0]; v.y = acc[i][1]; v.z = acc[i][2]; v.w = acc[i][3];
            int c = col0 + tx * TN;
            if (bias) { v.x += bias[c]; v.y += bias[c+1]; v.z += bias[c+2]; v.w += bias[c+3]; }
            if (relu) { v.x = fmaxf(v.x,0.f); v.y = fmaxf(v.y,0.f);
                        v.z = fmaxf(v.z,0.f); v.w = fmaxf(v.w,0.f); }
            *reinterpret_cast<float4*>(&C[r * N + c]) = v;
        }
    } else {
        float* dstp = Cp + z * MN;
#pragma unroll
        for (int i = 0; i < TM; ++i) {
            int r = row0 + ty * TM + i;
            float4 v;
            v.x = acc[i][0]; v.y = acc[i][1]; v.z = acc[i][2]; v.w = acc[i][3];
            *reinterpret_cast<float4*>(&dstp[r * N + col0 + tx * TN]) = v;
        }
    }
}

// ---------- split-K reduce: C = relu?(sum_z Cp[z] + bias) ----------
__global__ void k_reduceK(const float* __restrict__ Cp, const float* __restrict__ bias,
                          float* __restrict__ C, int MN, int N, int nz, int relu) {
    int i4 = (blockIdx.x * 256 + threadIdx.x) * 4;
    if (i4 >= MN) return;
    float4 acc = *reinterpret_cast<const float4*>(&Cp[i4]);
    for (int z = 1; z < nz; ++z) {
        float4 t = *reinterpret_cast<const float4*>(&Cp[z * MN + i4]);
        acc.x += t.x; acc.y += t.y; acc.z += t.z; acc.w += t.w;
    }
    if (bias) {
        int c = i4 % N;
        acc.x += bias[c]; acc.y += bias[c + 1]; acc.z += bias[c + 2]; acc.w += bias[c + 3];
    }
    if (relu) {
        acc.x = fmaxf(acc.x, 0.f); acc.y = fmaxf(acc.y, 0.f);
        acc.z = fmaxf(acc.z, 0.f); acc.w = fmaxf(acc.w, 0.f);
    }
    *reinterpret_cast<float4*>(&C[i4]) = acc;
}

// ---------- NNConv message, sorted grouped-GEMM form ----------
// block = (combo, grp): 64 edges of one combo. W staged transposed in LDS once,
// hoisted to 64 VGPRs per thread (col o). x rows gathered cooperatively (TLP).
// Compute: float4 LDS broadcasts x register W. Atomic scatter (proven exact).
__global__ __launch_bounds__(256) void k_msgg(
    const float* __restrict__ x, const float* __restrict__ wtab,
    const int* __restrict__ offs, const int2* __restrict__ esd,
    float* __restrict__ out) {
    const int c   = blockIdx.x >> 2;
    const int grp = blockIdx.x & 3;
    const int t = threadIdx.x;
    const int o = t & 31, slot = t >> 5;
    const int e0 = offs[c];
    const int n_c = offs[c + 1] - e0;
    if (grp * 64 >= n_c) return;               // block-uniform

    __shared__ float swT[32][65];              // [o][k], pad 65 -> conflict-free
    __shared__ float sx[64][64];
    __shared__ int ssrc[64], sdst[64];

    // stage W transposed (coalesced global reads, conflict-free LDS writes)
#pragma unroll
    for (int j = 0; j < 8; ++j) {
        int i = t + j * 256;                   // i = k*32 + o
        swT[i & 31][i >> 5] = wtab[c * 2048 + i];
    }
    __syncthreads();
    float wr[64];                              // this thread's W column
#pragma unroll
    for (int k = 0; k < 64; ++k) wr[k] = swT[o][k];

    for (int base = grp * 64; base < n_c; base += NGRP * 64) {
        int n_e = min(64, n_c - base);
        __syncthreads();                       // prev compute done before restage
        if (t < n_e) {
            int2 sd = esd[e0 + base + t];
            ssrc[t] = sd.x; sdst[t] = sd.y;
        }
        __syncthreads();
#pragma unroll
        for (int i = 0; i < 16; ++i) {         // gather x rows, 256B coalesced
            int idx = t + i * 256;
            int r = idx >> 6, d = idx & 63;
            if (r < n_e) sx[r][d] = x[ssrc[r] * 64 + d];
        }
        __syncthreads();
#pragma unroll
        for (int j = 0; j < 8; ++j) {          // slot's 8 edges
            int ei = slot * 8 + j;
            if (ei < n_e) {
                const float4* xv = reinterpret_cast<const float4*>(sx[ei]);
                float acc = 0.f;
#pragma unroll
                for (int k4 = 0; k4 < 16; ++k4) {
                    float4 xq = xv[k4];
                    acc += xq.x * wr[k4 * 4 + 0];
                    acc += xq.y * wr[k4 * 4 + 1];
                    acc += xq.z * wr[k4 * 4 + 2];
                    acc += xq.w * wr[k4 * 4 + 3];
                }
                atomicAdd(&out[sdst[ei] * 32 + o], acc);
            }
        }
    }
}

// ---------- fused readout tail: f1 -> f2 -> f3 -> f4 -> out, 4 graphs/block --
__global__ __launch_bounds__(256) void k_tail2(
    const float* __restrict__ f1,
    const float* __restrict__ mW2, const float* __restrict__ mb2,
    const float* __restrict__ mW3, const float* __restrict__ mb3,
    const float* __restrict__ mW4, const float* __restrict__ mb4,
    const float* __restrict__ mW5, const float* __restrict__ mb5,
    float* __restrict__ outv) {
    __shared__ float s1[4][256];
    __shared__ float s2[4][128];
    __shared__ float s3[4][32];
    __shared__ float s4[4][8];
    const int t  = threadIdx.x;
    const int g0 = blockIdx.x * 4;
#pragma unroll
    for (int i = 0; i < 4; ++i) {
        int idx = t + i * 256;
        s1[idx >> 8][idx & 255] = f1[g0 * 256 + idx];
    }
    __syncthreads();
#pragma unroll
    for (int i = 0; i < 2; ++i) {
        int idx = t + i * 256;
        int g = idx >> 7, cc = idx & 127;
        float acc = mb2[cc];
#pragma unroll 8
        for (int k = 0; k < 256; ++k) acc += s1[g][k] * mW2[k * 128 + cc];
        s2[g][cc] = fmaxf(acc, 0.f);
    }
    __syncthreads();
    const int w = t >> 6, lane = t & 63;
    if (lane < 32) {
        float acc = mb3[lane];
#pragma unroll 8
        for (int k = 0; k < 128; ++k) acc += s2[w][k] * mW3[k * 32 + lane];
        s3[w][lane] = fmaxf(acc, 0.f);
    }
    __syncthreads();
    if (lane < 8) {
        float acc = mb4[lane];
#pragma unroll
        for (int k = 0; k < 32; ++k) acc += s3[w][k] * mW4[k * 8 + lane];
        s4[w][lane] = fmaxf(acc, 0.f);
    }
    __syncthreads();
    if (lane == 0) {
        float acc = mb5[0];
#pragma unroll
        for (int k = 0; k < 8; ++k) acc += s4[w][k] * mW5[k];
        outv[g0 + w] = acc;
    }
}

extern "C" void kernel_launch(void* const* d_in, const int* in_sizes, int n_in,
                              void* d_out, int out_size, void* d_ws, size_t ws_size,
                              hipStream_t stream) {
    const int*   nf      = (const int*)d_in[0];
    const int*   ef      = (const int*)d_in[1];
    const int*   eidx    = (const int*)d_in[2];
    const float* atom_emb= (const float*)d_in[4];
    const float* bond_emb= (const float*)d_in[5];
    const float* gW1     = (const float*)d_in[6];
    const float* gW2     = (const float*)d_in[7];
    const float* gW3     = (const float*)d_in[8];
    const float* root    = (const float*)d_in[9];
    const float* cbias   = (const float*)d_in[10];
    const float* mW1     = (const float*)d_in[11];
    const float* mb1     = (const float*)d_in[12];
    const float* mW2     = (const float*)d_in[13];
    const float* mb2     = (const float*)d_in[14];
    const float* mW3     = (const float*)d_in[15];
    const float* mb3     = (const float*)d_in[16];
    const float* mW4     = (const float*)d_in[17];
    const float* mb4     = (const float*)d_in[18];
    const float* mW5     = (const float*)d_in[19];
    const float* mb5     = (const float*)d_in[20];

    const int* src = eidx;
    const int* dst = eidx + NEDGES;

    float* ws = (float*)d_ws;
    float* x    = ws;                        // 40960*64   = 2621440
    float* out  = x + 2621440;               // 40960*32   = 1310720
    float* h1   = out + 1310720;             // 512*1024   = 524288
    float* h2   = h1 + 524288;               // 512*256    = 131072
    float* wtab = h2 + 131072;               // 512*2048   = 1048576
    float* f1   = wtab + 1048576;            // 1024*256   = 262144
    float* part = f1 + 262144;               // 2097152 (8 MB split-K partials)
    int*   cid  = (int*)(part + 2097152);    // 81920
    int*   bh   = cid + 81920;               // 320*512 = 163840
    int*   offs = bh + 163840;               // 513
    int2*  esd  = (int2*)(offs + 1024);      // 81920 int2 (aligned)

    // 1. fused atom encoder + root transform
    k_node<<<NNODES / 4, 256, 0, stream>>>(nf, atom_emb, root, cbias, x, out);
    // 2. counting-sort by combo: hist -> scan -> scatter (no contended atomics)
    k_hist<<<NHB, 256, 0, stream>>>(ef, cid, bh);
    k_scan<<<1, 512, 0, stream>>>(bh, offs);
    k_scatter<<<NHB, 256, 0, stream>>>(cid, src, dst, bh, esd);
    // 3. h1 = relu(etab @ gW1), etab computed in-LDS per block
    k_h1<<<NCOMBO * 4, 256, 0, stream>>>(bond_emb, gW1, h1);
    // 4. h2 = relu(h1 @ gW2): 512x256, K=1024, split 16x64
    k_gemm_tiled<64, 64, 16, 4, 4><<<dim3(4, 8, 16), 256, 0, stream>>>(
        h1, gW2, nullptr, nullptr, part, NCOMBO, 256, 1024, 64, 0);
    k_reduceK<<<131072 / 1024, 256, 0, stream>>>(part, nullptr, h2, 131072, 256, 16, 1);
    // 5. wtab = h2 @ gW3: 512x2048, K=256, split 2x128
    k_gemm_tiled<64, 64, 16, 4, 4><<<dim3(32, 8, 2), 256, 0, stream>>>(
        h2, gW3, nullptr, nullptr, part, NCOMBO, 2048, 256, 128, 0);
    k_reduceK<<<1048576 / 1024, 256, 0, stream>>>(part, nullptr, wtab, 1048576, 2048, 2, 0);
    // 6. per-edge messages: sorted grouped-GEMM + atomic scatter
    k_msgg<<<NCOMBO * NGRP, 256, 0, stream>>>(x, wtab, offs, esd, out);
    // 7. f1 = relu(dense @ mW1 + mb1): 1024x256, K=1280, split 8x160
    k_gemm_tiled<64, 64, 16, 4, 4><<<dim3(4, 16, 8), 256, 0, stream>>>(
        out, mW1, nullptr, nullptr, part, NG, 256, 1280, 160, 0);
    k_reduceK<<<262144 / 1024, 256, 0, stream>>>(part, mb1, f1, 262144, 256, 8, 1);
    // 8. fused tail: f2, f3, f4, final
    k_tail2<<<NG / 4, 256, 0, stream>>>(f1, mW2, mb2, mW3, mb3, mW4, mb4,
                                        mW5, mb5, (float*)d_out);
}

// Round 11
// 236.988 us; speedup vs baseline: 1.1326x; 1.1326x over previous
//
#include <hip/hip_runtime.h>

#define NNODES 40960
#define NEDGES 81920
#define NG     1024
#define NCOMBO 512
#define NHB    320      // NEDGES/256 histogram blocks
#define NGRP   4        // edge-groups per combo in k_msgg

// ---------- fused node encoder: x[n,:], then out_init[n,:] = bias + x@root ---
__global__ __launch_bounds__(256) void k_node(
    const int* __restrict__ nf, const float* __restrict__ emb,
    const float* __restrict__ root, const float* __restrict__ bias,
    float* __restrict__ x, float* __restrict__ out) {
    __shared__ float sx[4][64];
    const int t = threadIdx.x;
    const int ln = t >> 6;                 // local node 0..3
    const int d  = t & 63;
    const int n  = blockIdx.x * 4 + ln;
    const int* nfr = nf + n * 9;
    float acc = 0.f;
#pragma unroll
    for (int c = 0; c < 9; ++c) {
        int idx = nfr[c];
        acc += emb[((c << 7) + idx) * 64 + d];
    }
    x[n * 64 + d] = acc;
    sx[ln][d] = acc;
    __syncthreads();
    if (d < 32) {
        float o = bias[d];
#pragma unroll
        for (int k = 0; k < 64; ++k) o += sx[ln][k] * root[k * 32 + d];
        out[n * 32 + d] = o;
    }
}

// ---------- h1[c,:] = relu(etab[c] @ gW1), etab computed in-LDS ----------
__global__ __launch_bounds__(256) void k_h1(
    const float* __restrict__ bemb, const float* __restrict__ gW1,
    float* __restrict__ h1) {
    __shared__ float se[16];
    const int b = blockIdx.x, t = threadIdx.x;
    const int c = b >> 2;
    const int n = ((b & 3) << 8) + t;
    if (t < 16) {
        int f0 = c >> 6, f1 = (c >> 3) & 7, f2 = c & 7;
        se[t] = bemb[f0 * 16 + t] + bemb[(8 + f1) * 16 + t] +
                bemb[(16 + f2) * 16 + t];
    }
    __syncthreads();
    float acc = 0.f;
#pragma unroll
    for (int k = 0; k < 16; ++k) acc += se[k] * gW1[k * 1024 + n];
    h1[c * 1024 + n] = fmaxf(acc, 0.f);
}

// ---------- sort prep 1: cid + per-block LDS histogram, combo-major bh -------
__global__ void k_hist(const int* __restrict__ ef, int* __restrict__ cid,
                       int* __restrict__ bh) {
    __shared__ int lh[512];
    const int t = threadIdx.x, b = blockIdx.x;
    lh[t] = 0; lh[t + 256] = 0;
    __syncthreads();
    int e = b * 256 + t;
    int c = (ef[e * 3] << 6) | (ef[e * 3 + 1] << 3) | ef[e * 3 + 2];
    cid[e] = c;
    atomicAdd(&lh[c], 1);                      // LDS atomic
    __syncthreads();
    bh[t * NHB + b]         = lh[t];           // combo-major layout
    bh[(t + 256) * NHB + b] = lh[t + 256];
}

// ---------- sort prep 2a: per-combo exclusive prefix over blocks (parallel) --
// 512 blocks (one per combo), coalesced 320-wide load, LDS Hillis-Steele.
__global__ __launch_bounds__(512) void k_scanA(int* __restrict__ bh,
                                               int* __restrict__ tot) {
    __shared__ int tmp[512];
    const int c = blockIdx.x, t = threadIdx.x;
    int v = (t < NHB) ? bh[c * NHB + t] : 0;
    tmp[t] = v;
    __syncthreads();
    for (int d = 1; d < 512; d <<= 1) {
        int add = (t >= d) ? tmp[t - d] : 0;
        __syncthreads();
        tmp[t] += add;
        __syncthreads();
    }
    if (t < NHB) bh[c * NHB + t] = tmp[t] - v; // exclusive within combo
    if (t == 511) tot[c] = tmp[511];
}

// ---------- sort prep 2b: exclusive scan of combo totals (1 block, LDS) ------
__global__ __launch_bounds__(512) void k_scanB(const int* __restrict__ tot,
                                               int* __restrict__ offs) {
    __shared__ int tmp[512];
    const int t = threadIdx.x;
    int v = tot[t];
    tmp[t] = v;
    __syncthreads();
    for (int d = 1; d < 512; d <<= 1) {
        int add = (t >= d) ? tmp[t - d] : 0;
        __syncthreads();
        tmp[t] += add;
        __syncthreads();
    }
    offs[t] = tmp[t] - v;
    if (t == 511) offs[512] = tmp[511];
}

// ---------- sort prep 3: scatter into packed (src,dst) sorted by cid ---------
__global__ void k_scatter(const int* __restrict__ cid, const int* __restrict__ src,
                          const int* __restrict__ dst, const int* __restrict__ bh,
                          const int* __restrict__ offs, int2* __restrict__ esd) {
    __shared__ int cur[512];
    const int t = threadIdx.x, b = blockIdx.x;
    cur[t]       = bh[t * NHB + b]         + offs[t];
    cur[t + 256] = bh[(t + 256) * NHB + b] + offs[t + 256];
    __syncthreads();
    int e = b * 256 + t;
    int p = atomicAdd(&cur[cid[e]], 1);        // LDS atomic, per-block
    esd[p] = make_int2(src[e], dst[e]);
}

// ---------- tiled GEMM, 64x64 block tile, 4x4 micro tile, split-K over z ------
template <int BM, int BN, int BK, int TM, int TN>
__global__ __launch_bounds__(256)
void k_gemm_tiled(const float* __restrict__ A, const float* __restrict__ B,
                  const float* __restrict__ bias, float* __restrict__ C,
                  float* __restrict__ Cp, int M, int N, int K, int KS, int relu) {
    constexpr int TX = BN / TN;                 // 16
    constexpr int TY = BM / TM;                 // 16
    static_assert(TX * TY == 256, "block must be 256 threads");
    __shared__ float As[BK][BM + 4];            // transposed A tile
    __shared__ float Bs[BK][BN + 4];
    const int tx = threadIdx.x % TX, ty = threadIdx.x / TX;
    const int row0 = blockIdx.y * BM, col0 = blockIdx.x * BN;
    const int z = blockIdx.z;
    const int k_begin = z * KS, k_end = k_begin + KS;

    const int am = threadIdx.x >> 2;            // 0..63
    const int ak = (threadIdx.x & 3) << 2;      // 0,4,8,12
    const int bk = threadIdx.x >> 4;            // 0..15
    const int bn = (threadIdx.x & 15) << 2;     // 0..60

    float acc[TM][TN] = {};
    for (int k0 = k_begin; k0 < k_end; k0 += BK) {
        float4 av = *reinterpret_cast<const float4*>(&A[(row0 + am) * K + k0 + ak]);
        float4 bv = *reinterpret_cast<const float4*>(&B[(k0 + bk) * N + col0 + bn]);
        As[ak + 0][am] = av.x;
        As[ak + 1][am] = av.y;
        As[ak + 2][am] = av.z;
        As[ak + 3][am] = av.w;
        *reinterpret_cast<float4*>(&Bs[bk][bn]) = bv;
        __syncthreads();
#pragma unroll
        for (int k = 0; k < BK; ++k) {
            float a[TM], b[TN];
            *reinterpret_cast<float4*>(a) =
                *reinterpret_cast<const float4*>(&As[k][ty * TM]);
            *reinterpret_cast<float4*>(b) =
                *reinterpret_cast<const float4*>(&Bs[k][tx * TN]);
#pragma unroll
            for (int i = 0; i < TM; ++i)
#pragma unroll
                for (int j = 0; j < TN; ++j) acc[i][j] += a[i] * b[j];
        }
        __syncthreads();
    }

    const int MN = M * N;
    if (gridDim.z == 1) {
#pragma unroll
        for (int i = 0; i < TM; ++i) {
            int r = row0 + ty * TM + i;
            float4 v;
            v.x = acc[i][0]; v.y = acc[i][1]; v.z = acc[i][2]; v.w = acc[i][3];
            int c = col0 + tx * TN;
            if (bias) { v.x += bias[c]; v.y += bias[c+1]; v.z += bias[c+2]; v.w += bias[c+3]; }
            if (relu) { v.x = fmaxf(v.x,0.f); v.y = fmaxf(v.y,0.f);
                        v.z = fmaxf(v.z,0.f); v.w = fmaxf(v.w,0.f); }
            *reinterpret_cast<float4*>(&C[r * N + c]) = v;
        }
    } else {
        float* dstp = Cp + z * MN;
#pragma unroll
        for (int i = 0; i < TM; ++i) {
            int r = row0 + ty * TM + i;
            float4 v;
            v.x = acc[i][0]; v.y = acc[i][1]; v.z = acc[i][2]; v.w = acc[i][3];
            *reinterpret_cast<float4*>(&dstp[r * N + col0 + tx * TN]) = v;
        }
    }
}

// ---------- split-K reduce: C = relu?(sum_z Cp[z] + bias) ----------
__global__ void k_reduceK(const float* __restrict__ Cp, const float* __restrict__ bias,
                          float* __restrict__ C, int MN, int N, int nz, int relu) {
    int i4 = (blockIdx.x * 256 + threadIdx.x) * 4;
    if (i4 >= MN) return;
    float4 acc = *reinterpret_cast<const float4*>(&Cp[i4]);
    for (int z = 1; z < nz; ++z) {
        float4 t = *reinterpret_cast<const float4*>(&Cp[z * MN + i4]);
        acc.x += t.x; acc.y += t.y; acc.z += t.z; acc.w += t.w;
    }
    if (bias) {
        int c = i4 % N;
        acc.x += bias[c]; acc.y += bias[c + 1]; acc.z += bias[c + 2]; acc.w += bias[c + 3];
    }
    if (relu) {
        acc.x = fmaxf(acc.x, 0.f); acc.y = fmaxf(acc.y, 0.f);
        acc.z = fmaxf(acc.z, 0.f); acc.w = fmaxf(acc.w, 0.f);
    }
    *reinterpret_cast<float4*>(&C[i4]) = acc;
}

// ---------- NNConv message, sorted grouped-GEMM form (unchanged from r10) ----
__global__ __launch_bounds__(256) void k_msgg(
    const float* __restrict__ x, const float* __restrict__ wtab,
    const int* __restrict__ offs, const int2* __restrict__ esd,
    float* __restrict__ out) {
    const int c   = blockIdx.x >> 2;
    const int grp = blockIdx.x & 3;
    const int t = threadIdx.x;
    const int o = t & 31, slot = t >> 5;
    const int e0 = offs[c];
    const int n_c = offs[c + 1] - e0;
    if (grp * 64 >= n_c) return;               // block-uniform

    __shared__ float swT[32][65];              // [o][k], pad 65 -> conflict-free
    __shared__ float sx[64][64];
    __shared__ int ssrc[64], sdst[64];

    // stage W transposed (coalesced global reads, conflict-free LDS writes)
#pragma unroll
    for (int j = 0; j < 8; ++j) {
        int i = t + j * 256;                   // i = k*32 + o
        swT[i & 31][i >> 5] = wtab[c * 2048 + i];
    }
    __syncthreads();
    float wr[64];                              // this thread's W column
#pragma unroll
    for (int k = 0; k < 64; ++k) wr[k] = swT[o][k];

    for (int base = grp * 64; base < n_c; base += NGRP * 64) {
        int n_e = min(64, n_c - base);
        __syncthreads();                       // prev compute done before restage
        if (t < n_e) {
            int2 sd = esd[e0 + base + t];
            ssrc[t] = sd.x; sdst[t] = sd.y;
        }
        __syncthreads();
#pragma unroll
        for (int i = 0; i < 16; ++i) {         // gather x rows, 256B coalesced
            int idx = t + i * 256;
            int r = idx >> 6, d = idx & 63;
            if (r < n_e) sx[r][d] = x[ssrc[r] * 64 + d];
        }
        __syncthreads();
#pragma unroll
        for (int j = 0; j < 8; ++j) {          // slot's 8 edges
            int ei = slot * 8 + j;
            if (ei < n_e) {
                const float4* xv = reinterpret_cast<const float4*>(sx[ei]);
                float acc = 0.f;
#pragma unroll
                for (int k4 = 0; k4 < 16; ++k4) {
                    float4 xq = xv[k4];
                    acc += xq.x * wr[k4 * 4 + 0];
                    acc += xq.y * wr[k4 * 4 + 1];
                    acc += xq.z * wr[k4 * 4 + 2];
                    acc += xq.w * wr[k4 * 4 + 3];
                }
                atomicAdd(&out[sdst[ei] * 32 + o], acc);
            }
        }
    }
}

// ---------- fused readout tail: f1 -> f2 -> f3 -> f4 -> out, 4 graphs/block --
__global__ __launch_bounds__(256) void k_tail2(
    const float* __restrict__ f1,
    const float* __restrict__ mW2, const float* __restrict__ mb2,
    const float* __restrict__ mW3, const float* __restrict__ mb3,
    const float* __restrict__ mW4, const float* __restrict__ mb4,
    const float* __restrict__ mW5, const float* __restrict__ mb5,
    float* __restrict__ outv) {
    __shared__ float s1[4][256];
    __shared__ float s2[4][128];
    __shared__ float s3[4][32];
    __shared__ float s4[4][8];
    const int t  = threadIdx.x;
    const int g0 = blockIdx.x * 4;
#pragma unroll
    for (int i = 0; i < 4; ++i) {
        int idx = t + i * 256;
        s1[idx >> 8][idx & 255] = f1[g0 * 256 + idx];
    }
    __syncthreads();
#pragma unroll
    for (int i = 0; i < 2; ++i) {
        int idx = t + i * 256;
        int g = idx >> 7, cc = idx & 127;
        float acc = mb2[cc];
#pragma unroll 8
        for (int k = 0; k < 256; ++k) acc += s1[g][k] * mW2[k * 128 + cc];
        s2[g][cc] = fmaxf(acc, 0.f);
    }
    __syncthreads();
    const int w = t >> 6, lane = t & 63;
    if (lane < 32) {
        float acc = mb3[lane];
#pragma unroll 8
        for (int k = 0; k < 128; ++k) acc += s2[w][k] * mW3[k * 32 + lane];
        s3[w][lane] = fmaxf(acc, 0.f);
    }
    __syncthreads();
    if (lane < 8) {
        float acc = mb4[lane];
#pragma unroll
        for (int k = 0; k < 32; ++k) acc += s3[w][k] * mW4[k * 8 + lane];
        s4[w][lane] = fmaxf(acc, 0.f);
    }
    __syncthreads();
    if (lane == 0) {
        float acc = mb5[0];
#pragma unroll
        for (int k = 0; k < 8; ++k) acc += s4[w][k] * mW5[k];
        outv[g0 + w] = acc;
    }
}

extern "C" void kernel_launch(void* const* d_in, const int* in_sizes, int n_in,
                              void* d_out, int out_size, void* d_ws, size_t ws_size,
                              hipStream_t stream) {
    const int*   nf      = (const int*)d_in[0];
    const int*   ef      = (const int*)d_in[1];
    const int*   eidx    = (const int*)d_in[2];
    const float* atom_emb= (const float*)d_in[4];
    const float* bond_emb= (const float*)d_in[5];
    const float* gW1     = (const float*)d_in[6];
    const float* gW2     = (const float*)d_in[7];
    const float* gW3     = (const float*)d_in[8];
    const float* root    = (const float*)d_in[9];
    const float* cbias   = (const float*)d_in[10];
    const float* mW1     = (const float*)d_in[11];
    const float* mb1     = (const float*)d_in[12];
    const float* mW2     = (const float*)d_in[13];
    const float* mb2     = (const float*)d_in[14];
    const float* mW3     = (const float*)d_in[15];
    const float* mb3     = (const float*)d_in[16];
    const float* mW4     = (const float*)d_in[17];
    const float* mb4     = (const float*)d_in[18];
    const float* mW5     = (const float*)d_in[19];
    const float* mb5     = (const float*)d_in[20];

    const int* src = eidx;
    const int* dst = eidx + NEDGES;

    float* ws = (float*)d_ws;
    float* x    = ws;                        // 40960*64   = 2621440
    float* out  = x + 2621440;               // 40960*32   = 1310720
    float* h1   = out + 1310720;             // 512*1024   = 524288
    float* h2   = h1 + 524288;               // 512*256    = 131072
    float* wtab = h2 + 131072;               // 512*2048   = 1048576
    float* f1   = wtab + 1048576;            // 1024*256   = 262144
    float* part = f1 + 262144;               // 2097152 (8 MB split-K partials)
    int*   cid  = (int*)(part + 2097152);    // 81920
    int*   bh   = cid + 81920;               // 512*320 = 163840 (combo-major)
    int*   tot  = bh + 163840;               // 512
    int*   offs = tot + 512;                 // 513 (padded to 1024)
    int2*  esd  = (int2*)(offs + 1024);      // 81920 int2 (8B-aligned)

    // 1. fused atom encoder + root transform
    k_node<<<NNODES / 4, 256, 0, stream>>>(nf, atom_emb, root, cbias, x, out);
    // 2. counting-sort by combo: hist -> parallel scan -> scatter
    k_hist<<<NHB, 256, 0, stream>>>(ef, cid, bh);
    k_scanA<<<NCOMBO, 512, 0, stream>>>(bh, tot);
    k_scanB<<<1, 512, 0, stream>>>(tot, offs);
    k_scatter<<<NHB, 256, 0, stream>>>(cid, src, dst, bh, offs, esd);
    // 3. h1 = relu(etab @ gW1), etab computed in-LDS per block
    k_h1<<<NCOMBO * 4, 256, 0, stream>>>(bond_emb, gW1, h1);
    // 4. h2 = relu(h1 @ gW2): 512x256, K=1024, split 16x64
    k_gemm_tiled<64, 64, 16, 4, 4><<<dim3(4, 8, 16), 256, 0, stream>>>(
        h1, gW2, nullptr, nullptr, part, NCOMBO, 256, 1024, 64, 0);
    k_reduceK<<<131072 / 1024, 256, 0, stream>>>(part, nullptr, h2, 131072, 256, 16, 1);
    // 5. wtab = h2 @ gW3: 512x2048, K=256, split 2x128
    k_gemm_tiled<64, 64, 16, 4, 4><<<dim3(32, 8, 2), 256, 0, stream>>>(
        h2, gW3, nullptr, nullptr, part, NCOMBO, 2048, 256, 128, 0);
    k_reduceK<<<1048576 / 1024, 256, 0, stream>>>(part, nullptr, wtab, 1048576, 2048, 2, 0);
    // 6. per-edge messages: sorted grouped-GEMM + atomic scatter
    k_msgg<<<NCOMBO * NGRP, 256, 0, stream>>>(x, wtab, offs, esd, out);
    // 7. f1 = relu(dense @ mW1 + mb1): 1024x256, K=1280, split 8x160
    k_gemm_tiled<64, 64, 16, 4, 4><<<dim3(4, 16, 8), 256, 0, stream>>>(
        out, mW1, nullptr, nullptr, part, NG, 256, 1280, 160, 0);
    k_reduceK<<<262144 / 1024, 256, 0, stream>>>(part, mb1, f1, 262144, 256, 8, 1);
    // 8. fused tail: f2, f3, f4, final
    k_tail2<<<NG / 4, 256, 0, stream>>>(f1, mW2, mb2, mW3, mb3, mW4, mb4,
                                        mW5, mb5, (float*)d_out);
}